// Round 1
// baseline (4348.862 us; speedup 1.0000x reference)
//
#include <hip/hip_runtime.h>
#include <math.h>

#define BQ 1024
#define TT 128
#define DD 128
#define HH 256
#define BB 16           // batch rows per block
#define NW 8            // waves per block
#define NTH (NW*64)

typedef float f32x4 __attribute__((ext_vector_type(4)));
typedef __bf16 bf16x8 __attribute__((ext_vector_type(8)));
typedef unsigned short u16x8 __attribute__((ext_vector_type(8)));
typedef unsigned short u16x4 __attribute__((ext_vector_type(4)));

// packed-weight tiles: each tile = one MFMA B-fragment set = 64 lanes x 8 bf16 = 1024 B
// B_hw[k = kb*32 + (lane>>4)*8 + e][n = nt*16 + (lane&15)] = W[n][k]
#define TW_DEC   0      // W_decay  N=256 K=128 : 16*4  = 64 tiles
#define TW_HIST  64     // W_hist   N=128 K=256 : 8*8   = 64
#define TW_WV    128    // Wv*off   N=128 K=128 : 8*4   = 32
#define TW_WR    160    // Wr*off   N=128 K=128 : 32
#define TW_WIH   192    // W_ih     N=768 K=256 : 48*8  = 384
#define TW_WHH   576    // W_hh     N=768 K=256 : 384
#define TW_TOTAL 960

__device__ __forceinline__ unsigned short f2bf(float f){
  union { float f; unsigned u; } v; v.f = f;
  unsigned r = v.u + 0x7FFFu + ((v.u >> 16) & 1u);
  return (unsigned short)(r >> 16);
}
__device__ __forceinline__ float bf2f(unsigned short u){
  union { unsigned u; float f; } v; v.u = ((unsigned)u) << 16; return v.f;
}
__device__ __forceinline__ float sigm(float v){ return 1.f/(1.f + __expf(-v)); }

__device__ __forceinline__ bf16x8 ldB(const unsigned short* wbf, int tile, int lane){
  return *(const bf16x8*)(wbf + (size_t)tile*512 + lane*8);
}
__device__ __forceinline__ f32x4 mfma16(bf16x8 a, bf16x8 b, f32x4 c){
  return __builtin_amdgcn_mfma_f32_16x16x32_bf16(a, b, c, 0, 0, 0);
}

// ---------------- pack weights (f32 row-major [N][K] -> bf16 B-fragment stream) --------
__global__ void pack_weights(const float* Wdec, const float* Whist, const float* Wv,
                             const float* Wr, const float* Wih, const float* Whh,
                             unsigned short* wbf){
  int gt = blockIdx.x * 4 + (threadIdx.x >> 6);
  int lane = threadIdx.x & 63;
  if (gt >= TW_TOTAL) return;
  const float* src; int K, tl; int dm = 0;
  if (gt < TW_HIST)      { src = Wdec;  K = DD;  tl = gt; }
  else if (gt < TW_WV)   { src = Whist; K = HH;  tl = gt - TW_HIST; }
  else if (gt < TW_WR)   { src = Wv;    K = DD;  tl = gt - TW_WV;  dm = 1; }
  else if (gt < TW_WIH)  { src = Wr;    K = DD;  tl = gt - TW_WR;  dm = 1; }
  else if (gt < TW_WHH)  { src = Wih;   K = 256; tl = gt - TW_WIH; }
  else                   { src = Whh;   K = 256; tl = gt - TW_WHH; }
  int nkb = K >> 5;
  int nt = tl / nkb, kb = tl - nt*nkb;
  int n  = nt*16 + (lane & 15);
  int k0 = kb*32 + (lane >> 4)*8;
  u16x8 pk;
  #pragma unroll
  for (int e = 0; e < 8; ++e){
    int k = k0 + e;
    float wv = src[(size_t)n*K + k];
    if (dm && n == k) wv = 0.f;   // zero-diagonal feature-regression mask
    pk[e] = f2bf(wv);
  }
  *(u16x8*)(wbf + (size_t)gt*512 + lane*8) = pk;
}

// ---------------- per-step mask sums M_t, zero loss numerators ----------------
__global__ void msum_kernel(const float* m, float* wsf){
  int t = blockIdx.x;
  float s = 0.f;
  for (int i = threadIdx.x; i < BQ*DD; i += 256){
    int b = i >> 7, d0 = i & 127;
    s += m[((size_t)b*TT + t)*DD + d0];
  }
  #pragma unroll
  for (int off = 32; off >= 1; off >>= 1) s += __shfl_down(s, off);
  __shared__ float ps[4];
  if ((threadIdx.x & 63) == 0) ps[threadIdx.x >> 6] = s;
  __syncthreads();
  if (threadIdx.x == 0){
    wsf[128 + t] = ps[0] + ps[1] + ps[2] + ps[3];
    wsf[t] = 0.f;
  }
}

// ---------------- final loss reduction ----------------
__global__ void loss_final(const float* wsf, float* out_loss){
  __shared__ float ps[TT];
  int t = threadIdx.x;
  ps[t] = wsf[t] / (wsf[128 + t] + 1e-5f);
  __syncthreads();
  if (t == 0){ float s = 0.f; for (int i = 0; i < TT; ++i) s += ps[i]; *out_loss = s; }
}

// ---------------- the recurrent scan ----------------
// LDS layout (bytes). bf16 tiles are row-major with XOR swizzle: byte ^= (row&7)<<4
#define L_H    0        // h'  [16][256] bf16, stride 512
#define L_D    8192     // d_t [16][128] bf16, stride 256
#define L_XB   12288    // xbar
#define L_M    16384    // m
#define L_XR   20480    // x_r
#define L_XI   24576    // x_imp
#define L_RED  28672    // 8 f32
#define L_HF   28704    // h final [16][256] f32 (post-loop only)
#define L_PS   45088    // 256 f32
#define L_TOT  46112

__global__ __launch_bounds__(NTH, 2) void scan_kernel(
    const float* __restrict__ x, const float* __restrict__ xhat,
    const float* __restrict__ m, const float* __restrict__ dly,
    const float* __restrict__ b_dec, const float* __restrict__ b_hist,
    const float* __restrict__ bv, const float* __restrict__ br,
    const float* __restrict__ conv_w, const float* __restrict__ conv_b,
    const float* __restrict__ b_ih, const float* __restrict__ b_hh,
    const float* __restrict__ W_out, const float* __restrict__ b_out,
    const unsigned short* __restrict__ wbf, float* __restrict__ lossN,
    float* __restrict__ out_ximp, float* __restrict__ out_y,
    float* __restrict__ out_ys, float* __restrict__ out_xu,
    float* __restrict__ out_xrs)
{
  __shared__ __align__(16) char lds[L_TOT];
  const int tid  = threadIdx.x;
  const int w    = tid >> 6;      // wave 0..7, owns h-cols [32w,32w+32), d-cols [16w,16w+16)
  const int lane = tid & 63;
  const int lr   = lane & 15;
  const int lg   = lane >> 4;
  const int b0   = blockIdx.x * BB;
  const int colD = w*16 + lr;

  const float bdec0 = b_dec[w*32 + lr];
  const float bdec1 = b_dec[w*32 + 16 + lr];
  const float bhist_v = b_hist[colD];
  const float bv_v = bv[colD];
  const float br_v = br[colD];
  float bihv[3][2], bhhv[3][2];
  #pragma unroll
  for (int g = 0; g < 3; ++g){
    bihv[g][0] = b_ih[g*256 + w*32 + lr];
    bihv[g][1] = b_ih[g*256 + w*32 + 16 + lr];
    bhhv[g][0] = b_hh[g*256 + w*32 + lr];
    bhhv[g][1] = b_hh[g*256 + w*32 + 16 + lr];
  }
  const float cw0 = conv_w[0], cw1 = conv_w[1], cbv = conv_b[0];
  const f32x4 z4 = {0.f, 0.f, 0.f, 0.f};

  // h state in registers, D-fragment layout: value (s,r) = h[row=lg*4+r][col=w*32+s*16+lr]
  float hst[2][4] = {{0.f,0.f,0.f,0.f},{0.f,0.f,0.f,0.f}};

  const int ldrow = tid >> 5;     // 0..15
  const int ldc4  = tid & 31;     // chunk of 4 floats
  const int lboff = (ldc4*8) ^ ((ldrow & 7) << 4);

  for (int t = 0; t < TT; ++t){
    // ---- stage x/xhat/m/d tile for this step into LDS (bf16, swizzled) ----
    {
      size_t gofs = ((size_t)(b0 + ldrow)*TT + t)*DD + ldc4*4;
      f32x4 xv = *(const f32x4*)(x + gofs);
      f32x4 hv = *(const f32x4*)(xhat + gofs);
      f32x4 mv = *(const f32x4*)(m + gofs);
      f32x4 dv = *(const f32x4*)(dly + gofs);
      u16x4 pxb, pm, pd;
      #pragma unroll
      for (int e = 0; e < 4; ++e){
        pxb[e] = f2bf(mv[e]*xv[e] + (1.f - mv[e])*hv[e]);
        pm[e]  = f2bf(mv[e]);
        pd[e]  = f2bf(dv[e]);
      }
      *(u16x4*)(lds + L_XB + ldrow*256 + lboff) = pxb;
      *(u16x4*)(lds + L_M  + ldrow*256 + lboff) = pm;
      *(u16x4*)(lds + L_D  + ldrow*256 + lboff) = pd;
    }
    __syncthreads();

    // ---- G0: gamma = exp(-relu(d @ Wdec^T + b_dec)); h' = h * gamma ----
    {
      bf16x8 df[4];
      #pragma unroll
      for (int kb = 0; kb < 4; ++kb)
        df[kb] = *(const bf16x8*)(lds + L_D + lr*256 + ((kb*64 + lg*16) ^ ((lr & 7) << 4)));
      f32x4 ga0 = z4, ga1 = z4;
      #pragma unroll
      for (int kb = 0; kb < 4; ++kb){
        ga0 = mfma16(df[kb], ldB(wbf, TW_DEC + (w*2+0)*4 + kb, lane), ga0);
        ga1 = mfma16(df[kb], ldB(wbf, TW_DEC + (w*2+1)*4 + kb, lane), ga1);
      }
      #pragma unroll
      for (int r = 0; r < 4; ++r){
        hst[0][r] *= __expf(-fmaxf(ga0[r] + bdec0, 0.f));
        hst[1][r] *= __expf(-fmaxf(ga1[r] + bdec1, 0.f));
      }
      #pragma unroll
      for (int s = 0; s < 2; ++s)
        #pragma unroll
        for (int r = 0; r < 4; ++r){
          int row = lg*4 + r, col = w*32 + s*16 + lr;
          *(unsigned short*)(lds + L_H + row*512 + ((col*2) ^ ((row & 7) << 4))) = f2bf(hst[s][r]);
        }
    }
    __syncthreads();

    // ---- G1: x_h = h'@W_hist^T ; G3: gh = h'@W_hh^T ; G5: xu = xbar@Wv_m^T ----
    bf16x8 hf[8];
    #pragma unroll
    for (int kb = 0; kb < 8; ++kb)
      hf[kb] = *(const bf16x8*)(lds + L_H + lr*512 + ((kb*64 + lg*16) ^ ((lr & 7) << 4)));
    f32x4 xhac = z4;
    #pragma unroll
    for (int kb = 0; kb < 8; ++kb)
      xhac = mfma16(hf[kb], ldB(wbf, TW_HIST + w*8 + kb, lane), xhac);
    f32x4 gh[3][2];
    #pragma unroll
    for (int g = 0; g < 3; ++g){ gh[g][0] = z4; gh[g][1] = z4; }
    #pragma unroll
    for (int g = 0; g < 3; ++g)
      #pragma unroll
      for (int s = 0; s < 2; ++s)
        #pragma unroll
        for (int kb = 0; kb < 8; ++kb)
          gh[g][s] = mfma16(hf[kb], ldB(wbf, TW_WHH + (g*16 + w*2 + s)*8 + kb, lane), gh[g][s]);
    f32x4 xuac = z4;
    #pragma unroll
    for (int kb = 0; kb < 4; ++kb){
      bf16x8 xb = *(const bf16x8*)(lds + L_XB + lr*256 + ((kb*64 + lg*16) ^ ((lr & 7) << 4)));
      xuac = mfma16(xb, ldB(wbf, TW_WV + w*4 + kb, lane), xuac);
    }

    // ---- x_r = m*x + (1-m)*(x_h + b_hist), stage to LDS ----
    float mreg[4], xreg[4];
    #pragma unroll
    for (int r = 0; r < 4; ++r){
      int row = lg*4 + r;
      mreg[r] = bf2f(*(const unsigned short*)(lds + L_M + row*256 + ((colD*2) ^ ((row & 7) << 4))));
      xreg[r] = x[((size_t)(b0 + row)*TT + t)*DD + colD];
      float xrin = mreg[r]*xreg[r] + (1.f - mreg[r])*(xhac[r] + bhist_v);
      *(unsigned short*)(lds + L_XR + row*256 + ((colD*2) ^ ((row & 7) << 4))) = f2bf(xrin);
    }
    __syncthreads();

    // ---- G2: xr = x_r@Wr_m^T + br ; outputs xu/xrs/x_imp ; loss partial ----
    f32x4 xrac = z4;
    #pragma unroll
    for (int kb = 0; kb < 4; ++kb){
      bf16x8 xr = *(const bf16x8*)(lds + L_XR + lr*256 + ((kb*64 + lg*16) ^ ((lr & 7) << 4)));
      xrac = mfma16(xr, ldB(wbf, TW_WR + w*4 + kb, lane), xrac);
    }
    float lpart = 0.f;
    #pragma unroll
    for (int r = 0; r < 4; ++r){
      int row = lg*4 + r;
      size_t go = ((size_t)(b0 + row)*TT + t)*DD + colD;
      float xrv = xrac[r] + br_v;
      float xuv = xuac[r] + bv_v;
      out_xrs[go] = xrv;
      out_xu[go]  = xuv;
      float xc = cw0*xuv + cw1*xrv + cbv;
      lpart += fabsf(xreg[r] - xc)*mreg[r];
      float xi = mreg[r]*xreg[r] + (1.f - mreg[r])*xc;
      out_ximp[go] = xi;
      *(unsigned short*)(lds + L_XI + row*256 + ((colD*2) ^ ((row & 7) << 4))) = f2bf(xi);
    }
    #pragma unroll
    for (int off = 32; off >= 1; off >>= 1) lpart += __shfl_down(lpart, off);
    if (lane == 0) ((float*)(lds + L_RED))[w] = lpart;
    __syncthreads();
    if (tid == 0){
      float s = 0.f;
      #pragma unroll
      for (int i = 0; i < NW; ++i) s += ((float*)(lds + L_RED))[i];
      atomicAdd(&lossN[t], s);
    }

    // ---- G4: gi = [x_imp, m]@W_ih^T ; gates ; h update ----
    {
      bf16x8 gif[8];
      #pragma unroll
      for (int kb = 0; kb < 4; ++kb)
        gif[kb] = *(const bf16x8*)(lds + L_XI + lr*256 + ((kb*64 + lg*16) ^ ((lr & 7) << 4)));
      #pragma unroll
      for (int kb = 0; kb < 4; ++kb)
        gif[4+kb] = *(const bf16x8*)(lds + L_M + lr*256 + ((kb*64 + lg*16) ^ ((lr & 7) << 4)));
      f32x4 gi[3][2];
      #pragma unroll
      for (int g = 0; g < 3; ++g){ gi[g][0] = z4; gi[g][1] = z4; }
      #pragma unroll
      for (int g = 0; g < 3; ++g)
        #pragma unroll
        for (int s = 0; s < 2; ++s)
          #pragma unroll
          for (int kb = 0; kb < 8; ++kb)
            gi[g][s] = mfma16(gif[kb], ldB(wbf, TW_WIH + (g*16 + w*2 + s)*8 + kb, lane), gi[g][s]);
      #pragma unroll
      for (int s = 0; s < 2; ++s)
        #pragma unroll
        for (int r = 0; r < 4; ++r){
          float rr = sigm(gi[0][s][r] + bihv[0][s] + gh[0][s][r] + bhhv[0][s]);
          float zz = sigm(gi[1][s][r] + bihv[1][s] + gh[1][s][r] + bhhv[1][s]);
          float nn = tanhf(gi[2][s][r] + bihv[2][s] + rr*(gh[2][s][r] + bhhv[2][s]));
          hst[s][r] = (1.f - zz)*nn + zz*hst[s][r];
        }
    }
    __syncthreads();
  }

  // ---- epilogue: y_out = h_fin @ W_out^T + b_out ; y_score = sigmoid ----
  float* hfin = (float*)(lds + L_HF);
  #pragma unroll
  for (int s = 0; s < 2; ++s)
    #pragma unroll
    for (int r = 0; r < 4; ++r)
      hfin[(lg*4 + r)*HH + w*32 + s*16 + lr] = hst[s][r];
  __syncthreads();
  float* psum = (float*)(lds + L_PS);
  if (tid < 256){
    int row = tid >> 4, seg = tid & 15;
    float p = 0.f;
    #pragma unroll
    for (int c = 0; c < 16; ++c) p += hfin[row*HH + seg*16 + c]*W_out[seg*16 + c];
    psum[tid] = p;
  }
  __syncthreads();
  if (tid < 16){
    float yv = b_out[0];
    #pragma unroll
    for (int i = 0; i < 16; ++i) yv += psum[tid*16 + i];
    out_y[b0 + tid] = yv;
    out_ys[b0 + tid] = sigm(yv);
  }
}

extern "C" void kernel_launch(void* const* d_in, const int* in_sizes, int n_in,
                              void* d_out, int out_size, void* d_ws, size_t ws_size,
                              hipStream_t stream){
  const float* x     = (const float*)d_in[0];
  const float* xhat  = (const float*)d_in[1];
  // d_in[2] = u (unused by reference)
  const float* m     = (const float*)d_in[3];
  const float* dly   = (const float*)d_in[4];
  const float* Wdec  = (const float*)d_in[5];
  const float* b_dec = (const float*)d_in[6];
  const float* Whist = (const float*)d_in[7];
  const float* b_hist= (const float*)d_in[8];
  const float* Wv    = (const float*)d_in[9];
  const float* bvv   = (const float*)d_in[10];
  const float* Wr    = (const float*)d_in[11];
  const float* brr   = (const float*)d_in[12];
  const float* convw = (const float*)d_in[13];
  const float* convb = (const float*)d_in[14];
  const float* Wih   = (const float*)d_in[15];
  const float* Whh   = (const float*)d_in[16];
  const float* b_ih  = (const float*)d_in[17];
  const float* b_hh  = (const float*)d_in[18];
  const float* W_out = (const float*)d_in[19];
  const float* b_out = (const float*)d_in[20];

  float* wsf = (float*)d_ws;                                   // [0..127] lossN, [128..255] M_t
  unsigned short* wbf = (unsigned short*)((char*)d_ws + 1024); // packed bf16 weights (~960 KB)

  float* out = (float*)d_out;
  size_t btd = (size_t)BQ*TT*DD;
  float* out_ximp = out;
  float* out_y    = out + btd;
  float* out_ys   = out_y + BQ;
  float* out_loss = out_ys + BQ;
  float* out_xu   = out_loss + 1;
  float* out_xrs  = out_xu + btd;

  pack_weights<<<TW_TOTAL/4, 256, 0, stream>>>(Wdec, Whist, Wv, Wr, Wih, Whh, wbf);
  msum_kernel<<<TT, 256, 0, stream>>>(m, wsf);
  scan_kernel<<<BQ/BB, NTH, 0, stream>>>(x, xhat, m, dly, b_dec, b_hist, bvv, brr,
      convw, convb, b_ih, b_hh, W_out, b_out, wbf, wsf,
      out_ximp, out_y, out_ys, out_xu, out_xrs);
  loss_final<<<1, TT, 0, stream>>>(wsf, out_loss);
}